// Round 12
// baseline (56.493 us; speedup 1.0000x reference)
//
#include <hip/hip_runtime.h>

// ---------- types ----------
typedef __attribute__((ext_vector_type(8))) short bf16x8;
typedef __attribute__((ext_vector_type(4))) float f32x4;
typedef __attribute__((ext_vector_type(16))) float f32x16;

__device__ __forceinline__ short f2bf(float f) {
  unsigned u = __builtin_bit_cast(unsigned, f);
  u += 0x7fffu + ((u >> 16) & 1u);   // round-to-nearest-even
  return (short)(u >> 16);
}

// ---------- layout ----------
// IN=4096, OUT=4096, RANK=1024, GROUP=128, PACK=8
// GEMM: out[n*4096+m] = sum_r W_V(m,r)*S(r) * W_U(r,n)
// 32x32x16 MFMA fragment-major storage; each 1 KB block = one fragment in
// lane order (lane*16B). Fragment mapping (A-side, 32x32x16 bf16):
//   row = lane&31, k = (lane>>5)*8 + e   (inferred from verified 16x16 rule)
// A: panel mp (128 rows) x kt (32k): blk = mi*2+kk (mi=32-row frag 0..3)
//   elem addr = ((mp*32+kt)*8  + blk)*512 + lane*8 + e
//   m = mp*128 + mi*32 + (lane&31); r = kt*32 + kk*16 + (lane>>5)*8 + e
// B: panel np (256 cols) x kt: blk = nj*2+kk (nj=32-col frag 0..7)
//   elem addr = ((np*32+kt)*16 + blk)*512 + lane*8 + e
//   n = np*256 + nj*32 + (lane&31); r = kt*32 + kk*16 + (lane>>5)*8 + e

// ---------- stage 1: fused dequant (V -> A, U -> B) ----------
__global__ __launch_bounds__(256) void dequant_fused(
    const int* __restrict__ qw_V, const int* __restrict__ qz_V,
    const float* __restrict__ sc_V, const float* __restrict__ S,
    short* __restrict__ A,
    const int* __restrict__ qw_U, const int* __restrict__ qz_U,
    const float* __restrict__ sc_U, short* __restrict__ B) {
  const int bid = blockIdx.x;
  if (bid < 2048) {
    const int t    = bid * 256 + threadIdx.x;      // 0..524287
    const int tile = t >> 9;                       // mp*32 + kt
    const int blk  = (t >> 6) & 7;                 // mi*2 + kk
    const int lane = t & 63;
    const int m  = (tile >> 5) * 128 + (blk >> 1) * 32 + (lane & 31);
    const int r0 = (tile & 31) * 32 + (blk & 1) * 16 + ((lane >> 5) << 3);
    const int g  = m >> 7;
    const int sh = (m & 7) << 2;
    const int zw = qz_V[(g << 7) + (r0 >> 3)];
    const int*   wq  = qw_V + (m >> 3) * 1024 + r0;
    const float* scp = sc_V + (g << 10) + r0;
    const float* sp  = S + r0;
    bf16x8 res;
#pragma unroll
    for (int e = 0; e < 8; ++e) {
      int q = (wq[e] >> sh) & 15;
      int z = ((zw >> (e << 2)) & 15) + 1;
      res[e] = f2bf((float)(q - z) * scp[e] * sp[e]);
    }
    *(bf16x8*)(A + ((size_t)t << 3)) = res;        // coalesced
  } else {
    const int t    = (bid - 2048) * 256 + threadIdx.x;
    const int tile = t >> 10;                      // np*32 + kt
    const int blk  = (t >> 6) & 15;                // nj*2 + kk
    const int lane = t & 63;
    const int n  = (tile >> 5) * 256 + (blk >> 1) * 32 + (lane & 31);
    const int r0 = (tile & 31) * 32 + (blk & 1) * 16 + ((lane >> 5) << 3);
    const int w  = qw_U[(r0 >> 3) * 4096 + n];
    const int g  = r0 >> 7;
    const int zw = qz_U[(g << 9) + (n >> 3)];
    const int z  = ((zw >> ((n & 7) << 2)) & 15) + 1;
    const float s = sc_U[(g << 12) + n];
    bf16x8 res;
#pragma unroll
    for (int e = 0; e < 8; ++e) {
      int q = (w >> (e << 2)) & 15;
      res[e] = f2bf((float)(q - z) * s);
    }
    *(bf16x8*)(B + ((size_t)t << 3)) = res;
  }
}

// ---------- stage 2: 128x256, BK=32, 8 waves, 32x32x16 MFMA ----------
// 1 block/CU (LDS padded to 80 KB), grid 512 -> 2 rounds: round-1 store
// tails drain under round-2 K-loops. Swizzle: np = xcd*2 + (idx>>5),
// mp = idx&31 -> each XCD-round touches ONE 512-KB B panel (L2-resident).
// Per K-step: 3 GLL (A 8KB: 1, B 16KB: 2), 8 ds_read_b128, 8 MFMA 32x32x16.
// vmcnt ledger (= R11's verified one): prologue STAGE(0,1) -> vmcnt(3);
// steady: reads; lgkm(0); BAR; STAGE(kt+2); MFMA; vmcnt(3); BAR.
// kt==30: vmcnt(0); kt==31: no stage/wait.
#define GLL(g, l)                                                              \
  __builtin_amdgcn_global_load_lds(                                            \
      (const __attribute__((address_space(1))) void*)(g),                      \
      (__attribute__((address_space(3))) void*)(l), 16, 0, 0)

__global__ __launch_bounds__(512, 2) void gemm128x256(
    const short* __restrict__ A, const short* __restrict__ B,
    float* __restrict__ out) {
  __shared__ __align__(16) char lds[81920];   // 2 bufs x 24 KB + pad -> 1 blk/CU
  const int tid  = threadIdx.x;          // 0..511
  const int lane = tid & 63;
  const int wid  = tid >> 6;             // 0..7
  const int wm   = wid >> 2;             // 0..1  (64-row half of 128)
  const int wn   = wid & 3;              // 0..3  (64-col quarter of 256)
  const int o    = blockIdx.x;
  const int xcd  = o & 7;
  const int idx  = o >> 3;               // 0..63
  const int np   = xcd * 2 + (idx >> 5); // one np per XCD per round
  const int mp   = idx & 31;

  // staging sources (per-lane tid*16B); LDS dests wave-uniform
  const short* gAp = A + (size_t)mp * 131072 + tid * 8;  // panel = 32*4096 elems
  const short* gBp = B + (size_t)np * 262144 + tid * 8;  // panel = 32*8192 elems

#define STAGE(kt) do {                                                         \
    const int bo_ = ((kt) & 1) * 24576;                                        \
    GLL(gAp + (size_t)(kt) * 4096,        lds + bo_ +         (wid << 10));    \
    GLL(gBp + (size_t)(kt) * 8192,        lds + bo_ + 8192 +  (wid << 10));    \
    GLL(gBp + (size_t)(kt) * 8192 + 4096, lds + bo_ + 16384 + (wid << 10));    \
  } while (0)

  // fragment read bases: A blk (wm*2+mi2)*2+kk at that*1024; B at +8192
  const char* Ard = lds + (lane << 4);
  const char* Brd = lds + 8192 + (lane << 4);

  f32x16 acc[2][2];
#pragma unroll
  for (int i = 0; i < 2; ++i)
#pragma unroll
    for (int j = 0; j < 2; ++j)
#pragma unroll
      for (int e = 0; e < 16; ++e) acc[i][j][e] = 0.f;

  // ---- prologue ----
  STAGE(0);
  STAGE(1);
  asm volatile("s_waitcnt vmcnt(3)" ::: "memory");
  __builtin_amdgcn_s_barrier();

  for (int kt = 0; kt < 32; ++kt) {
    const int bo = (kt & 1) * 24576;
    bf16x8 a[2][2], b[2][2];
#pragma unroll
    for (int mi2 = 0; mi2 < 2; ++mi2)
#pragma unroll
      for (int kk = 0; kk < 2; ++kk)
        a[mi2][kk] = *(const bf16x8*)(Ard + bo +
                       (((wm * 2 + mi2) * 2 + kk) << 10));
#pragma unroll
    for (int nj2 = 0; nj2 < 2; ++nj2)
#pragma unroll
      for (int kk = 0; kk < 2; ++kk)
        b[nj2][kk] = *(const bf16x8*)(Brd + bo +
                       (((wn * 2 + nj2) * 2 + kk) << 10));
    asm volatile("s_waitcnt lgkmcnt(0)" ::: "memory");
    __builtin_amdgcn_sched_barrier(0);
    __builtin_amdgcn_s_barrier();        // all waves' reads of this buf done
    if (kt < 30) STAGE(kt + 2);          // overwrite now-safe buf
    __builtin_amdgcn_s_setprio(1);
#pragma unroll
    for (int kk = 0; kk < 2; ++kk)
#pragma unroll
      for (int mi2 = 0; mi2 < 2; ++mi2)
#pragma unroll
        for (int nj2 = 0; nj2 < 2; ++nj2)
          acc[mi2][nj2] = __builtin_amdgcn_mfma_f32_32x32x16_bf16(
              a[mi2][kk], b[nj2][kk], acc[mi2][nj2], 0, 0, 0);
    __builtin_amdgcn_s_setprio(0);
    if (kt < 30)       asm volatile("s_waitcnt vmcnt(3)" ::: "memory");
    else if (kt == 30) asm volatile("s_waitcnt vmcnt(0)" ::: "memory");
    if (kt < 31) __builtin_amdgcn_s_barrier();   // publish tile kt+1
  }

  // epilogue: out[n*4096+m]; C map (verified m74/m101):
  // col(n)=lane&31, row(m)=(reg&3)+8*(reg>>2)+4*(lane>>5)
#pragma unroll
  for (int mi2 = 0; mi2 < 2; ++mi2)
#pragma unroll
    for (int nj2 = 0; nj2 < 2; ++nj2) {
      const int mb = mp * 128 + wm * 64 + mi2 * 32 + ((lane >> 5) << 2);
      const int nb = np * 256 + wn * 64 + nj2 * 32 + (lane & 31);
      const f32x16 c = acc[mi2][nj2];
#pragma unroll
      for (int q = 0; q < 4; ++q) {
        f32x4 v = {c[q * 4], c[q * 4 + 1], c[q * 4 + 2], c[q * 4 + 3]};
        *(f32x4*)(out + (size_t)nb * 4096 + mb + 8 * q) = v;
      }
    }
#undef STAGE
}

// ---------- launcher ----------
// setup_inputs order: 0:x 1:qweight_V 2:qzeros_V 3:scales_V 4:g_idx_V
//                     5:qweight_U 6:qzeros_U 7:scales_U 8:g_idx_U 9:S
extern "C" void kernel_launch(void* const* d_in, const int* in_sizes, int n_in,
                              void* d_out, int out_size, void* d_ws, size_t ws_size,
                              hipStream_t stream) {
  const int*   qw_V = (const int*)d_in[1];
  const int*   qz_V = (const int*)d_in[2];
  const float* sc_V = (const float*)d_in[3];
  const int*   qw_U = (const int*)d_in[5];
  const int*   qz_U = (const int*)d_in[6];
  const float* sc_U = (const float*)d_in[7];
  const float* S    = (const float*)d_in[9];

  short* A = (short*)d_ws;                  // 8 MB fragment-major (V*S)
  short* B = (short*)d_ws + 4096 * 1024;    // 8 MB fragment-major U^T
  float* out = (float*)d_out;

  dequant_fused<<<4096, 256, 0, stream>>>(qw_V, qz_V, sc_V, S, A,
                                          qw_U, qz_U, sc_U, B);
  gemm128x256<<<512, 512, 0, stream>>>(A, B, out);
}